// Round 11
// baseline (151.339 us; speedup 1.0000x reference)
//
#include <hip/hip_runtime.h>

#define B 256
#define EPSV 1e-5f

// ---------- output offsets (f32 elements) ----------
#define OFF_ASSIGN 0
#define OFF_LOSS   256
#define OFF_ACT4   257
#define OFF_L1     2817
#define OFF_L2     12847873
#define OFF_L3     14486273

__device__ __forceinline__ void wave_reduce2(float& s, float& q) {
#pragma unroll
    for (int o = 32; o > 0; o >>= 1) {
        s += __shfl_down(s, o, 64);
        q += __shfl_down(q, o, 64);
    }
}

// sense-reversing grid barrier; (cnt,gen) dedicated per barrier instance.
// Agent-scope atomics + threadfence give cross-XCD visibility of prior plain stores.
__device__ __forceinline__ void gbar(unsigned* cnt, unsigned* gen) {
    __syncthreads();
    if (threadIdx.x == 0) {
        __threadfence();
        unsigned g = __hip_atomic_load(gen, __ATOMIC_RELAXED, __HIP_MEMORY_SCOPE_AGENT);
        unsigned a = __hip_atomic_fetch_add(cnt, 1u, __ATOMIC_ACQ_REL, __HIP_MEMORY_SCOPE_AGENT);
        if (a == gridDim.x - 1) {
            __hip_atomic_store(cnt, 0u, __ATOMIC_RELAXED, __HIP_MEMORY_SCOPE_AGENT);
            __hip_atomic_fetch_add(gen, 1u, __ATOMIC_RELEASE, __HIP_MEMORY_SCOPE_AGENT);
        } else {
            while (__hip_atomic_load(gen, __ATOMIC_ACQUIRE, __HIP_MEMORY_SCOPE_AGENT) == g)
                __builtin_amdgcn_s_sleep(1);
        }
    }
    __syncthreads();
}

// One persistent block per batch element. All activations stay in LDS.
__global__ __launch_bounds__(512, 4) void fused_kernel(
        const float* __restrict__ inp, const float* __restrict__ c1w,
        const float* __restrict__ c1b, const float* __restrict__ g1,
        const float* __restrict__ bb1, const float* __restrict__ c2w,
        const float* __restrict__ c2b, const float* __restrict__ g2,
        const float* __restrict__ bb2, const float* __restrict__ f1w,
        const float* __restrict__ f1b, const float* __restrict__ f2w,
        const float* __restrict__ f2b, const float* __restrict__ k1s,
        const float* __restrict__ k2s, const float* __restrict__ k3s,
        float* __restrict__ out, unsigned* __restrict__ bar,
        float* __restrict__ part1, float* __restrict__ part2,
        float* __restrict__ lossb, float* __restrict__ w1t,
        float* __restrict__ k3st) {
    int b = blockIdx.x, tid = threadIdx.x;
    int lane = tid & 63, wid = tid >> 6;     // 8 waves

    __shared__ __align__(16) float si[3072]; // input image; reused in phase 2
    __shared__ __align__(16) float act[4704];
    __shared__ float cw[450];
    __shared__ float cb1[6];
    __shared__ float sk1[384];
    __shared__ float w2s[2400];
    __shared__ float c2bs[16];
    __shared__ float xp[1176];
    __shared__ float sa[1600];
    __shared__ float wpart[96];
    __shared__ float chs[16], chq[16], ssc[16], ssh[16];
    __shared__ float a3r[120], a3p[120];
    __shared__ float wsum[8], wmv[8];
    __shared__ int wmi[8];
    __shared__ float rfin[256];
    // phase-2 aliases into si (input image dead after conv1)
    float* sk2   = si;          // 1024
    float* xs    = si + 1024;   // 400
    float* partq = si + 1424;   // 512 (4x128)
    float* sv    = si + 1936;   // 512  (byte off 7744, 16B-aligned)

    // ================= phase 0: conv1 (+ weight transpose) =================
    for (int i = tid; i < 3072; i += 512) si[i] = inp[b * 3072 + i];
    for (int i = tid; i < 450; i += 512) cw[i] = c1w[i];
    if (tid < 6) cb1[tid] = c1b[tid];
    if (tid < 16) c2bs[tid] = c2b[tid];
    for (int i = tid; i < 384; i += 512) sk1[i] = k1s[i];
    for (int i = tid; i < 2400; i += 512) w2s[i] = c2w[i];
    {   // each block transposes a 428-elem chunk of w1T/k3sT
        int idx = b * 428 + tid;
        if (tid < 428 && idx < 109440) {
            if (idx < 48000) { int c = idx / 120, o = idx % 120; w1t[idx] = f1w[o * 400 + c]; }
            else { int j = idx - 48000; int c = j >> 9, k = j & 511; k3st[j] = k3s[k * 120 + c]; }
        }
    }
    __syncthreads();
    float s6[6], q6[6];
#pragma unroll
    for (int c = 0; c < 6; ++c) { s6[c] = 0.f; q6[c] = 0.f; }
#pragma unroll
    for (int c = 0; c < 6; ++c) {
        for (int hw = tid; hw < 784; hw += 512) {
            int oh = hw / 28, ow = hw % 28;
            float acc = cb1[c];
#pragma unroll
            for (int ic = 0; ic < 3; ++ic) {
                const float* ip = si + ic * 1024 + oh * 32 + ow;
                const float* wp = cw + c * 75 + ic * 25;
#pragma unroll
                for (int kh = 0; kh < 5; ++kh)
#pragma unroll
                    for (int kw = 0; kw < 5; ++kw)
                        acc += ip[kh * 32 + kw] * wp[kh * 5 + kw];
            }
            act[c * 784 + hw] = acc;
            s6[c] += acc; q6[c] += acc * acc;
        }
    }
#pragma unroll
    for (int c = 0; c < 6; ++c) {
        wave_reduce2(s6[c], q6[c]);
        if (lane == 0) { wpart[(wid * 6 + c) * 2] = s6[c]; wpart[(wid * 6 + c) * 2 + 1] = q6[c]; }
    }
    __syncthreads();
    if (tid < 6) {
        float S = 0.f, Q = 0.f;
#pragma unroll
        for (int w = 0; w < 8; ++w) { S += wpart[(w * 6 + tid) * 2]; Q += wpart[(w * 6 + tid) * 2 + 1]; }
        part1[(b * 6 + tid) * 2] = S;
        part1[(b * 6 + tid) * 2 + 1] = Q;
    }
    gbar(bar + 0, bar + 1);

    // ================= phase 1: stats1 + BN + logits1 + pool + conv2 =================
    if (wid < 6) {
        float s = 0.f, q = 0.f;
#pragma unroll
        for (int j = 0; j < 4; ++j) {
            int bi = lane + 64 * j;
            s += part1[(bi * 6 + wid) * 2];
            q += part1[(bi * 6 + wid) * 2 + 1];
        }
        wave_reduce2(s, q);
        if (lane == 0) { chs[wid] = s; chq[wid] = q; }
    }
    __syncthreads();
    if (tid < 6) {
        float m = chs[tid] * (1.f / 200704.f);
        float v = chq[tid] * (1.f / 200704.f) - m * m;
        float sc = g1[tid] * rsqrtf(v + EPSV);
        ssc[tid] = sc; ssh[tid] = bb1[tid] - m * sc;
    }
    __syncthreads();
    for (int i = tid; i < 4704; i += 512) {
        int c = i / 784;
        act[i] = act[i] * ssc[c] + ssh[c];
    }
    __syncthreads();
    float* op = out + OFF_L1 + (long)b * 50176;
    for (int i = tid; i < 50176; i += 512) {
        int k = i / 784, hw = i - k * 784;
        const float* kp = sk1 + k * 6;
        float d0 = act[hw]        - kp[0];
        float d1 = act[784 + hw]  - kp[1];
        float d2 = act[1568 + hw] - kp[2];
        float d3 = act[2352 + hw] - kp[3];
        float d4 = act[3136 + hw] - kp[4];
        float d5 = act[3920 + hw] - kp[5];
        op[i] = -sqrtf(d0*d0 + d1*d1 + d2*d2 + d3*d3 + d4*d4 + d5*d5);
    }
    for (int i = tid; i < 1176; i += 512) {
        int c = i / 196, p = i % 196, ph = p / 14, pw = p % 14;
        const float* ap = act + c * 784 + ph * 56 + pw * 2;
        float m = fmaxf(fmaxf(ap[0], ap[1]), fmaxf(ap[28], ap[29]));
        xp[i] = fmaxf(m, 0.f);
    }
    __syncthreads();
    for (int i = tid; i < 1600; i += 512) {
        int c = i / 100, hw = i - c * 100;
        int oh = hw / 10, ow = hw - oh * 10;
        float acc = c2bs[c];
#pragma unroll
        for (int ic = 0; ic < 6; ++ic) {
            const float* xsrc = xp + ic * 196 + oh * 14 + ow;
            const float* wp = w2s + c * 150 + ic * 25;
#pragma unroll
            for (int kh = 0; kh < 5; ++kh)
#pragma unroll
                for (int kw = 0; kw < 5; ++kw)
                    acc += xsrc[kh * 14 + kw] * wp[kh * 5 + kw];
        }
        sa[i] = acc;
    }
    __syncthreads();
#pragma unroll
    for (int r = 0; r < 2; ++r) {            // wave handles channels 2w, 2w+1
        int cc = wid * 2 + r;
        float s = 0.f, q = 0.f;
        if (lane < 100) { float x = sa[cc * 100 + lane]; s = x; q = x * x; }
        if (lane < 36)  { float x = sa[cc * 100 + 64 + lane]; s += x; q += x * x; }
        wave_reduce2(s, q);
        if (lane == 0) { part2[(b * 16 + cc) * 2] = s; part2[(b * 16 + cc) * 2 + 1] = q; }
    }
    gbar(bar + 2, bar + 3);

    // ================= phase 2: stats2 + BN + logits2 + pool + head =================
#pragma unroll
    for (int r = 0; r < 2; ++r) {
        int ch = wid + r * 8;
        float s = 0.f, q = 0.f;
#pragma unroll
        for (int j = 0; j < 4; ++j) {
            int bi = lane + 64 * j;
            s += part2[(bi * 16 + ch) * 2];
            q += part2[(bi * 16 + ch) * 2 + 1];
        }
        wave_reduce2(s, q);
        if (lane == 0) { chs[ch] = s; chq[ch] = q; }
    }
    for (int i = tid; i < 1024; i += 512) sk2[i] = k2s[i];
    __syncthreads();
    if (tid < 16) {
        float m = chs[tid] * (1.f / 25600.f);
        float v = chq[tid] * (1.f / 25600.f) - m * m;
        float sc = g2[tid] * rsqrtf(v + EPSV);
        ssc[tid] = sc; ssh[tid] = bb2[tid] - m * sc;
    }
    __syncthreads();
    for (int i = tid; i < 1600; i += 512) {
        int c = i / 100;
        sa[i] = sa[i] * ssc[c] + ssh[c];
    }
    __syncthreads();
    float* op2 = out + OFF_L2 + (long)b * 6400;
    for (int i = tid; i < 6400; i += 512) {
        int k = i / 100, hw = i - k * 100;
        float s = 0.f;
#pragma unroll
        for (int c = 0; c < 16; ++c) { float d = sa[c * 100 + hw] - sk2[k * 16 + c]; s += d * d; }
        op2[i] = -sqrtf(s);
    }
    for (int i = tid; i < 400; i += 512) {
        int c = i / 25, p = i % 25, ph = p / 5, pw = p % 5;
        const float* ap = sa + c * 100 + ph * 20 + pw * 2;
        float m = fmaxf(fmaxf(ap[0], ap[1]), fmaxf(ap[10], ap[11]));
        xs[i] = fmaxf(m, 0.f);
    }
    __syncthreads();
    {   // fc1: 4-way K-split, coalesced w1t columns
        int o = tid & 127, q4 = tid >> 7;
        float s = 0.f;
        if (o < 120) {
            const float* wp = w1t + (q4 * 100) * 120 + o;
            const float* xq = xs + q4 * 100;
#pragma unroll 10
            for (int c = 0; c < 100; ++c) s += xq[c] * wp[c * 120];
        }
        partq[q4 * 128 + o] = s;
    }
    __syncthreads();
    if (tid < 120) {
        float acc = f1b[tid] + partq[tid] + partq[128 + tid] + partq[256 + tid] + partq[384 + tid];
        a3r[tid] = acc;
        a3p[tid] = fmaxf(acc, 0.f);
    }
    __syncthreads();
    float v;
    {   // logits3: thread = key, coalesced k3st columns (L2-resident)
        const float* kp = k3st + tid;
        float s = 0.f;
#pragma unroll 8
        for (int c = 0; c < 120; ++c) { float d = a3r[c] - kp[c * 512]; s += d * d; }
        v = -sqrtf(s);
        sv[tid] = v;
        out[OFF_L3 + (long)b * 512 + tid] = v;
    }
    if (tid < 10) {
        float acc = f2b[tid];
        const float* wp = f2w + tid * 120;
#pragma unroll 8
        for (int c = 0; c < 120; ++c) acc += a3p[c] * wp[c];
        out[OFF_ACT4 + b * 10 + tid] = acc;
    }
    __syncthreads();
    // rank of this value (ties by index) == sorted position; sum v^2 exp(-rank)
    const float4* sv4 = reinterpret_cast<const float4*>(sv);
    int cnt = 0;
#pragma unroll 8
    for (int j4 = 0; j4 < 128; ++j4) {
        float4 o4 = sv4[j4];
        int jb = j4 * 4;
        cnt += (o4.x < v || (o4.x == v && jb < tid)) ? 1 : 0;
        cnt += (o4.y < v || (o4.y == v && jb + 1 < tid)) ? 1 : 0;
        cnt += (o4.z < v || (o4.z == v && jb + 2 < tid)) ? 1 : 0;
        cnt += (o4.w < v || (o4.w == v && jb + 3 < tid)) ? 1 : 0;
    }
    float contrib = v * v * expf(-(float)cnt);
    float ssum = contrib;
#pragma unroll
    for (int o = 32; o > 0; o >>= 1) ssum += __shfl_down(ssum, o, 64);
    float mv = v; int mi = tid;
#pragma unroll
    for (int o = 32; o > 0; o >>= 1) {
        float ov = __shfl_down(mv, o, 64);
        int oi = __shfl_down(mi, o, 64);
        if (ov > mv || (ov == mv && oi < mi)) { mv = ov; mi = oi; }
    }
    if (lane == 0) { wsum[wid] = ssum; wmv[wid] = mv; wmi[wid] = mi; }
    __syncthreads();
    if (tid == 0) {
        float tot = 0.f;
        float bmv = wmv[0]; int bmi = wmi[0];
#pragma unroll
        for (int w = 0; w < 8; ++w) {
            tot += wsum[w];
            if (wmv[w] > bmv || (wmv[w] == bmv && wmi[w] < bmi)) { bmv = wmv[w]; bmi = wmi[w]; }
        }
        lossb[b] = tot;
        out[OFF_ASSIGN + b] = (float)bmi;
    }
    __syncthreads();

    // ================= phase 3: arrive-only barrier; block 0 reduces loss =================
    if (tid == 0) {
        __threadfence();
        __hip_atomic_fetch_add(bar + 4, 1u, __ATOMIC_ACQ_REL, __HIP_MEMORY_SCOPE_AGENT);
    }
    if (b != 0) return;
    if (tid == 0) {
        while (__hip_atomic_load(bar + 4, __ATOMIC_ACQUIRE, __HIP_MEMORY_SCOPE_AGENT) < 256u)
            __builtin_amdgcn_s_sleep(1);
    }
    __syncthreads();
    if (tid < 256) rfin[tid] = lossb[tid];
    __syncthreads();
    for (int s2 = 128; s2 > 0; s2 >>= 1) {
        if (tid < s2 && tid < 256) rfin[tid] += rfin[tid + s2];
        __syncthreads();
    }
    if (tid == 0) out[OFF_LOSS] = rfin[0] * (1.f / 256.f);
}

extern "C" void kernel_launch(void* const* d_in, const int* in_sizes, int n_in,
                              void* d_out, int out_size, void* d_ws, size_t ws_size,
                              hipStream_t stream) {
    const float* inp = (const float*)d_in[0];
    const float* c1w = (const float*)d_in[1];
    const float* c1b = (const float*)d_in[2];
    const float* g1  = (const float*)d_in[3];
    const float* bb1 = (const float*)d_in[4];
    const float* c2w = (const float*)d_in[5];
    const float* c2b = (const float*)d_in[6];
    const float* g2  = (const float*)d_in[7];
    const float* bb2 = (const float*)d_in[8];
    const float* f1w = (const float*)d_in[9];
    const float* f1b = (const float*)d_in[10];
    const float* f2w = (const float*)d_in[11];
    const float* f2b = (const float*)d_in[12];
    const float* k1  = (const float*)d_in[13];
    const float* k2  = (const float*)d_in[14];
    const float* k3  = (const float*)d_in[15];
    float* out = (float*)d_out;

    float* W = (float*)d_ws;
    unsigned* bar = (unsigned*)d_ws;    // bar[0..15] (64 B), zeroed each launch
    float* part1 = W + 64;              // 3072
    float* part2 = W + 3136;            // 8192
    float* lossb = W + 11328;           // 256
    float* w1t   = W + 11584;           // 48000  (w1T [400][120])
    float* k3st  = W + 59584;           // 61440  (k3sT [120][512])

    hipMemsetAsync(d_ws, 0, 64, stream);   // reset barrier state every replay
    fused_kernel<<<B, 512, 0, stream>>>(inp, c1w, c1b, g1, bb1, c2w, c2b, g2, bb2,
                                        f1w, f1b, f2w, f2b, k1, k2, k3,
                                        out, bar, part1, part2, lossb, w1t, k3st);
}

// Round 12
// 140.995 us; speedup vs baseline: 1.0734x; 1.0734x over previous
//
#include <hip/hip_runtime.h>

#define B 256
#define EPSV 1e-5f

// ---------- output offsets (f32 elements) ----------
#define OFF_ASSIGN 0
#define OFF_LOSS   256
#define OFF_ACT4   257
#define OFF_L1     2817
#define OFF_L2     12847873
#define OFF_L3     14486273

__device__ __forceinline__ void wave_reduce2(float& s, float& q) {
#pragma unroll
    for (int o = 32; o > 0; o >>= 1) {
        s += __shfl_down(s, o, 64);
        q += __shfl_down(q, o, 64);
    }
}

// sense-reversing grid barrier; (cnt,gen) dedicated per barrier instance.
__device__ __forceinline__ void gbar(unsigned* cnt, unsigned* gen) {
    __syncthreads();
    if (threadIdx.x == 0) {
        __threadfence();
        unsigned g = __hip_atomic_load(gen, __ATOMIC_RELAXED, __HIP_MEMORY_SCOPE_AGENT);
        unsigned a = __hip_atomic_fetch_add(cnt, 1u, __ATOMIC_ACQ_REL, __HIP_MEMORY_SCOPE_AGENT);
        if (a == gridDim.x - 1) {
            __hip_atomic_store(cnt, 0u, __ATOMIC_RELAXED, __HIP_MEMORY_SCOPE_AGENT);
            __hip_atomic_fetch_add(gen, 1u, __ATOMIC_RELEASE, __HIP_MEMORY_SCOPE_AGENT);
        } else {
            while (__hip_atomic_load(gen, __ATOMIC_ACQUIRE, __HIP_MEMORY_SCOPE_AGENT) == g)
                __builtin_amdgcn_s_sleep(1);
        }
    }
    __syncthreads();
}

// One persistent block per batch element, 1024 threads (16 waves).
__global__ __launch_bounds__(1024) void fused_kernel(
        const float* __restrict__ inp, const float* __restrict__ c1w,
        const float* __restrict__ c1b, const float* __restrict__ g1,
        const float* __restrict__ bb1, const float* __restrict__ c2w,
        const float* __restrict__ c2b, const float* __restrict__ g2,
        const float* __restrict__ bb2, const float* __restrict__ f1w,
        const float* __restrict__ f1b, const float* __restrict__ f2w,
        const float* __restrict__ f2b, const float* __restrict__ k1s,
        const float* __restrict__ k2s, const float* __restrict__ k3s,
        float* __restrict__ out, unsigned* __restrict__ bar,
        float* __restrict__ part1, float* __restrict__ part2,
        float* __restrict__ lossb, float* __restrict__ w1t,
        float* __restrict__ k3st) {
    int b = blockIdx.x, tid = threadIdx.x;
    int lane = tid & 63, wid = tid >> 6;     // 16 waves

    __shared__ __align__(16) float si[3072];  // input; phase-2 scratch
    __shared__ __align__(16) float act[4704]; // act1; phase-2 scratch
    __shared__ float cw[450], cb1[6], sk1[384], k2sq1[64];
    __shared__ float w2s[2400], c2bs[16];
    __shared__ float xp[1176];
    __shared__ __align__(16) float sa[1600];
    __shared__ float k2sq2[64];
    __shared__ float wpart[192];
    __shared__ float chs[16], chq[16], ssc[16], ssh[16];
    __shared__ float a3r[120], a3p[120];
    __shared__ float wsum[8], wmv[8];
    __shared__ int wmi[8];
    // phase-2 aliases
    float* sk2   = si;           // 1024
    float* xs    = si + 1024;    // 400
    float* partq = si + 1424;    // 1024 (8x128)
    float* sv    = si + 2448;    // 512 (byte 9792, 16B aligned)
    float* pv    = act;          // 1024 (2x512)
    int*   cntp  = (int*)(act + 1024); // 1024
    float* rfin  = act + 2048;   // 256

    // ================= phase 0: loads + conv1 + transpose =================
    for (int i = tid; i < 3072; i += 1024) si[i] = inp[b * 3072 + i];
    if (tid < 450) cw[tid] = c1w[tid];
    if (tid < 6) cb1[tid] = c1b[tid];
    if (tid < 16) c2bs[tid] = c2b[tid];
    if (tid < 384) sk1[tid] = k1s[tid];
    for (int i = tid; i < 2400; i += 1024) w2s[i] = c2w[i];
    {   // transpose one 428-elem chunk per block
        int idx = b * 428 + tid;
        if (tid < 428 && idx < 109440) {
            if (idx < 48000) { int c = idx / 120, o = idx % 120; w1t[idx] = f1w[o * 400 + c]; }
            else { int j = idx - 48000; int c = j >> 9, k = j & 511; k3st[j] = k3s[k * 120 + c]; }
        }
    }
    __syncthreads();
    float s6[6], q6[6];
#pragma unroll
    for (int c = 0; c < 6; ++c) { s6[c] = 0.f; q6[c] = 0.f; }
    if (tid < 784) {
        int oh = tid / 28, ow = tid % 28;
#pragma unroll
        for (int c = 0; c < 6; ++c) {
            float acc = cb1[c];
#pragma unroll
            for (int ic = 0; ic < 3; ++ic) {
                const float* ip = si + ic * 1024 + oh * 32 + ow;
                const float* wp = cw + c * 75 + ic * 25;
#pragma unroll
                for (int kh = 0; kh < 5; ++kh)
#pragma unroll
                    for (int kw = 0; kw < 5; ++kw)
                        acc += ip[kh * 32 + kw] * wp[kh * 5 + kw];
            }
            act[c * 784 + tid] = acc;
            s6[c] = acc; q6[c] = acc * acc;
        }
    }
#pragma unroll
    for (int c = 0; c < 6; ++c) {
        wave_reduce2(s6[c], q6[c]);
        if (lane == 0) { wpart[wid * 12 + c * 2] = s6[c]; wpart[wid * 12 + c * 2 + 1] = q6[c]; }
    }
    __syncthreads();
    if (tid < 6) {
        float S = 0.f, Q = 0.f;
#pragma unroll
        for (int w = 0; w < 16; ++w) { S += wpart[w * 12 + tid * 2]; Q += wpart[w * 12 + tid * 2 + 1]; }
        part1[(b * 6 + tid) * 2] = S;
        part1[(b * 6 + tid) * 2 + 1] = Q;
    }
    gbar(bar + 0, bar + 1);

    // ================= phase 1: stats1 + BN + logits1 + pool + conv2 =================
    if (wid < 6) {
        float s = 0.f, q = 0.f;
#pragma unroll
        for (int j = 0; j < 4; ++j) {
            int bi = lane + 64 * j;
            s += part1[(bi * 6 + wid) * 2];
            q += part1[(bi * 6 + wid) * 2 + 1];
        }
        wave_reduce2(s, q);
        if (lane == 0) { chs[wid] = s; chq[wid] = q; }
    }
    if (tid >= 512 && tid < 576) {           // K2 for layer-1 keys (wave 8)
        int k = tid - 512;
        float s = 0.f;
#pragma unroll
        for (int c = 0; c < 6; ++c) { float x = sk1[k * 6 + c]; s += x * x; }
        k2sq1[k] = s;
    }
    __syncthreads();
    if (tid < 6) {
        float m = chs[tid] * (1.f / 200704.f);
        float v = chq[tid] * (1.f / 200704.f) - m * m;
        float sc = g1[tid] * rsqrtf(v + EPSV);
        ssc[tid] = sc; ssh[tid] = bb1[tid] - m * sc;
    }
    __syncthreads();
    for (int i = tid; i < 4704; i += 1024) {
        int c = i / 784;
        act[i] = act[i] * ssc[c] + ssh[c];
    }
    __syncthreads();
    if (tid < 784) {                          // logits1: act in regs, k-outer, dot form
        float a0 = act[tid], a1 = act[784 + tid], a2 = act[1568 + tid];
        float a3 = act[2352 + tid], a4 = act[3136 + tid], a5 = act[3920 + tid];
        float A2 = a0*a0 + a1*a1 + a2*a2 + a3*a3 + a4*a4 + a5*a5;
        float* op = out + OFF_L1 + (long)b * 50176 + tid;
#pragma unroll 4
        for (int k = 0; k < 64; ++k) {
            const float* kp = sk1 + k * 6;
            float dot = a0*kp[0] + a1*kp[1] + a2*kp[2] + a3*kp[3] + a4*kp[4] + a5*kp[5];
            float r = fmaxf(A2 + k2sq1[k] - 2.f * dot, 0.f);
            *op = -sqrtf(r);
            op += 784;
        }
    } else {                                  // pool on spare threads
        for (int i = tid - 784; i < 1176; i += 240) {
            int c = i / 196, p = i % 196, ph = p / 14, pw = p % 14;
            const float* ap = act + c * 784 + ph * 56 + pw * 2;
            float m = fmaxf(fmaxf(ap[0], ap[1]), fmaxf(ap[28], ap[29]));
            xp[i] = fmaxf(m, 0.f);
        }
    }
    __syncthreads();
    for (int i = tid; i < 1600; i += 1024) {
        int c = i / 100, hw = i - c * 100;
        int oh = hw / 10, ow = hw - oh * 10;
        float acc = c2bs[c];
#pragma unroll
        for (int ic = 0; ic < 6; ++ic) {
            const float* xsrc = xp + ic * 196 + oh * 14 + ow;
            const float* wp = w2s + c * 150 + ic * 25;
#pragma unroll
            for (int kh = 0; kh < 5; ++kh)
#pragma unroll
                for (int kw = 0; kw < 5; ++kw)
                    acc += xsrc[kh * 14 + kw] * wp[kh * 5 + kw];
        }
        sa[i] = acc;
    }
    __syncthreads();
    {   // per-channel partials: wave = channel (16 waves)
        float s = 0.f, q = 0.f;
        if (lane < 100) { float x = sa[wid * 100 + lane]; s = x; q = x * x; }
        if (lane < 36)  { float x = sa[wid * 100 + 64 + lane]; s += x; q += x * x; }
        wave_reduce2(s, q);
        if (lane == 0) { part2[(b * 16 + wid) * 2] = s; part2[(b * 16 + wid) * 2 + 1] = q; }
    }
    gbar(bar + 2, bar + 3);

    // ================= phase 2: stats2 + BN + logits2 + pool + head =================
    {   // stats2: wave = channel
        float s = 0.f, q = 0.f;
#pragma unroll
        for (int j = 0; j < 4; ++j) {
            int bi = lane + 64 * j;
            s += part2[(bi * 16 + wid) * 2];
            q += part2[(bi * 16 + wid) * 2 + 1];
        }
        wave_reduce2(s, q);
        if (lane == 0) { chs[wid] = s; chq[wid] = q; }
    }
    sk2[tid] = k2s[tid];                      // 1024 elems, 1 per thread
    __syncthreads();
    if (tid < 16) {
        float m = chs[tid] * (1.f / 25600.f);
        float v = chq[tid] * (1.f / 25600.f) - m * m;
        float sc = g2[tid] * rsqrtf(v + EPSV);
        ssc[tid] = sc; ssh[tid] = bb2[tid] - m * sc;
    }
    if (tid >= 64 && tid < 128) {             // K2 for layer-2 keys
        int k = tid - 64;
        float s = 0.f;
#pragma unroll
        for (int c = 0; c < 16; ++c) { float x = sk2[k * 16 + c]; s += x * x; }
        k2sq2[k] = s;
    }
    __syncthreads();
    for (int i = tid; i < 1600; i += 1024) {
        int c = i / 100;
        sa[i] = sa[i] * ssc[c] + ssh[c];
    }
    __syncthreads();
    if (tid < 800) {                          // logits2: act in regs, k-eighth per thread
        int kg = tid / 100, hw = tid - kg * 100;
        float a[16], A2 = 0.f;
#pragma unroll
        for (int c = 0; c < 16; ++c) { a[c] = sa[c * 100 + hw]; A2 += a[c] * a[c]; }
        float* op2 = out + OFF_L2 + (long)b * 6400 + kg * 800 + hw;
#pragma unroll
        for (int k = kg * 8; k < kg * 8 + 8; ++k) {
            const float* kp = sk2 + k * 16;
            float dot = 0.f;
#pragma unroll
            for (int c = 0; c < 16; ++c) dot += a[c] * kp[c];
            *op2 = -sqrtf(fmaxf(A2 + k2sq2[k] - 2.f * dot, 0.f));
            op2 += 100;
        }
    } else {                                  // pool on spare threads
        for (int i = tid - 800; i < 400; i += 224) {
            int c = i / 25, p = i % 25, ph = p / 5, pw = p % 5;
            const float* ap = sa + c * 100 + ph * 20 + pw * 2;
            float m = fmaxf(fmaxf(ap[0], ap[1]), fmaxf(ap[10], ap[11]));
            xs[i] = fmaxf(m, 0.f);
        }
    }
    __syncthreads();
    {   // fc1: 8-way K-split, coalesced w1t columns
        int o = tid & 127, q8 = tid >> 7;
        float s = 0.f;
        if (o < 120) {
            const float* wp = w1t + (q8 * 50) * 120 + o;
            const float* xq = xs + q8 * 50;
#pragma unroll 10
            for (int c = 0; c < 50; ++c) s += xq[c] * wp[c * 120];
        }
        partq[q8 * 128 + o] = s;
    }
    __syncthreads();
    if (tid < 120) {
        float acc = f1b[tid];
#pragma unroll
        for (int q8 = 0; q8 < 8; ++q8) acc += partq[q8 * 128 + tid];
        a3r[tid] = acc;
        a3p[tid] = fmaxf(acc, 0.f);
    }
    __syncthreads();
    {   // logits3: 2 threads per key, coalesced k3st columns
        int k = tid & 511, h = tid >> 9;
        const float* kp = k3st + k;
        float s = 0.f;
#pragma unroll 6
        for (int c = h * 60; c < h * 60 + 60; ++c) {
            float d = a3r[c] - kp[c * 512];
            s += d * d;
        }
        pv[h * 512 + k] = s;
    }
    if (tid < 10) {
        float acc = f2b[tid];
        const float* wp = f2w + tid * 120;
#pragma unroll 8
        for (int c = 0; c < 120; ++c) acc += a3p[c] * wp[c];
        out[OFF_ACT4 + b * 10 + tid] = acc;
    }
    __syncthreads();
    if (tid < 512) {
        float v = -sqrtf(pv[tid] + pv[512 + tid]);
        sv[tid] = v;
        out[OFF_L3 + (long)b * 512 + tid] = v;
    }
    __syncthreads();
    {   // rank scan: 2 threads per value
        int i = tid & 511, h = tid >> 9;
        float v = sv[i];
        const float4* sv4 = reinterpret_cast<const float4*>(sv);
        int cnt = 0;
#pragma unroll 8
        for (int j4 = h * 64; j4 < h * 64 + 64; ++j4) {
            float4 o4 = sv4[j4];
            int jb = j4 * 4;
            cnt += (o4.x < v || (o4.x == v && jb < i)) ? 1 : 0;
            cnt += (o4.y < v || (o4.y == v && jb + 1 < i)) ? 1 : 0;
            cnt += (o4.z < v || (o4.z == v && jb + 2 < i)) ? 1 : 0;
            cnt += (o4.w < v || (o4.w == v && jb + 3 < i)) ? 1 : 0;
        }
        cntp[h * 512 + i] = cnt;
    }
    __syncthreads();
    if (tid < 512) {
        float v = sv[tid];
        int cnt = cntp[tid] + cntp[512 + tid];
        float contrib = v * v * expf(-(float)cnt);
        float ssum = contrib;
#pragma unroll
        for (int o = 32; o > 0; o >>= 1) ssum += __shfl_down(ssum, o, 64);
        float mv = v; int mi = tid;
#pragma unroll
        for (int o = 32; o > 0; o >>= 1) {
            float ov = __shfl_down(mv, o, 64);
            int oi = __shfl_down(mi, o, 64);
            if (ov > mv || (ov == mv && oi < mi)) { mv = ov; mi = oi; }
        }
        if (lane == 0) { wsum[wid] = ssum; wmv[wid] = mv; wmi[wid] = mi; }
    }
    __syncthreads();
    if (tid == 0) {
        float tot = 0.f;
        float bmv = wmv[0]; int bmi = wmi[0];
#pragma unroll
        for (int w = 0; w < 8; ++w) {
            tot += wsum[w];
            if (wmv[w] > bmv || (wmv[w] == bmv && wmi[w] < bmi)) { bmv = wmv[w]; bmi = wmi[w]; }
        }
        lossb[b] = tot;
        out[OFF_ASSIGN + b] = (float)bmi;
    }
    __syncthreads();

    // ================= phase 3: arrive; block 0 reduces loss =================
    if (tid == 0) {
        __threadfence();
        __hip_atomic_fetch_add(bar + 4, 1u, __ATOMIC_ACQ_REL, __HIP_MEMORY_SCOPE_AGENT);
    }
    if (b != 0) return;
    if (tid == 0) {
        while (__hip_atomic_load(bar + 4, __ATOMIC_ACQUIRE, __HIP_MEMORY_SCOPE_AGENT) < 256u)
            __builtin_amdgcn_s_sleep(1);
    }
    __syncthreads();
    if (tid < 256) rfin[tid] = lossb[tid];
    __syncthreads();
    for (int s2 = 128; s2 > 0; s2 >>= 1) {
        if (tid < s2) rfin[tid] += rfin[tid + s2];
        __syncthreads();
    }
    if (tid == 0) out[OFF_LOSS] = rfin[0] * (1.f / 256.f);
}

extern "C" void kernel_launch(void* const* d_in, const int* in_sizes, int n_in,
                              void* d_out, int out_size, void* d_ws, size_t ws_size,
                              hipStream_t stream) {
    const float* inp = (const float*)d_in[0];
    const float* c1w = (const float*)d_in[1];
    const float* c1b = (const float*)d_in[2];
    const float* g1  = (const float*)d_in[3];
    const float* bb1 = (const float*)d_in[4];
    const float* c2w = (const float*)d_in[5];
    const float* c2b = (const float*)d_in[6];
    const float* g2  = (const float*)d_in[7];
    const float* bb2 = (const float*)d_in[8];
    const float* f1w = (const float*)d_in[9];
    const float* f1b = (const float*)d_in[10];
    const float* f2w = (const float*)d_in[11];
    const float* f2b = (const float*)d_in[12];
    const float* k1  = (const float*)d_in[13];
    const float* k2  = (const float*)d_in[14];
    const float* k3  = (const float*)d_in[15];
    float* out = (float*)d_out;

    float* W = (float*)d_ws;
    unsigned* bar = (unsigned*)d_ws;    // 64 B, zeroed each launch
    float* part1 = W + 64;              // 3072
    float* part2 = W + 3136;            // 8192
    float* lossb = W + 11328;           // 256
    float* w1t   = W + 11584;           // 48000
    float* k3st  = W + 59584;           // 61440

    hipMemsetAsync(d_ws, 0, 64, stream);
    fused_kernel<<<B, 1024, 0, stream>>>(inp, c1w, c1b, g1, bb1, c2w, c2b, g2, bb2,
                                         f1w, f1b, f2w, f2b, k1, k2, k3,
                                         out, bar, part1, part2, lossb, w1t, k3st);
}